// Round 10
// baseline (574.069 us; speedup 1.0000x reference)
//
#include <hip/hip_runtime.h>
#include <math.h>

#define BLOCK 256
#define NN 100
#define NSLAB 128         // anchor slabs per image (blocks); slab = 512 anchors
#define GA 2              // anchors per thread
#define FLAG 0x40000000   // "override winner" marker in box_indice

__device__ __forceinline__ float fast_rcp(float x) { return __builtin_amdgcn_rcpf(x); }

// ---------------------------------------------------------------------------
// Single-pass match: block = (image, 512-anchor slab), grid 8*128 = 1024.
// Row (per-anchor) max/argmax: thread-local, sole writer — exact first-box
// via strict >. Column (per-box) max/argmax: thread-local over 2 anchors,
// then monotone-filtered LDS atomicMax on packed (iou<<32 | ~anchor):
//   - broadcast ds_read of sbest[n] (same addr across wave = free)
//   - atomicMax only if candidate beats current (stale read safe: skip only
//     when LDS already >= candidate; extra atomics harmless)
// No shfl chains, no barriers in the hot loop.
// ---------------------------------------------------------------------------
__global__ void __launch_bounds__(BLOCK) bbp_match(
    const float* __restrict__ anchors,            // [A,4] cbox (cx,cy,w,h)
    const float* __restrict__ bboxes,             // [B,N,4] bbox
    float* __restrict__ max_iou_anchor,           // [B,A]
    int* __restrict__ box_indice,                 // [B,A]
    unsigned long long* __restrict__ packed_part, // [NSLAB][B*N] partial-major
    int A, int BN) {
    const int bid = blockIdx.x;
    const int b = bid >> 7;                 // / NSLAB
    const int slab = bid & (NSLAB - 1);
    const int tid = threadIdx.x;
    const int abase = slab * (GA * BLOCK);

    __shared__ unsigned long long sbest[NN];    // 800 B
    if (tid < NN) sbest[tid] = 0ull;

    // per-thread anchor geometry (registers)
    float ax1[GA], ay1[GA], ax2[GA], ay2[GA], aar[GA];
    #pragma unroll
    for (int g = 0; g < GA; ++g) {
        const int a = abase + g * BLOCK + tid;
        const float4 ac = *(const float4*)(anchors + (size_t)a * 4);
        ax1[g] = fmaf(ac.z, -0.5f, ac.x);
        ay1[g] = fmaf(ac.w, -0.5f, ac.y);
        ax2[g] = fmaf(ac.z, 0.5f, ac.x);
        ay2[g] = fmaf(ac.w, 0.5f, ac.y);
        aar[g] = ac.z * ac.w;
    }
    float best[GA];
    int bi[GA];
    #pragma unroll
    for (int g = 0; g < GA; ++g) { best[g] = -1.0f; bi[g] = 0; }

    const float* bbase = bboxes + (size_t)b * NN * 4;      // wave-uniform
    __syncthreads();

    #pragma unroll 5
    for (int n = 0; n < NN; ++n) {
        const float4 v = *(const float4*)(bbase + 4 * n);  // uniform -> s_load
        const float sa = (v.z - v.x) * (v.w - v.y);
        float cbest = -1.0f;
        unsigned ca = 0;
        #pragma unroll
        for (int g = 0; g < GA; ++g) {
            float lx = fmaxf(ax1[g], v.x), ly = fmaxf(ay1[g], v.y);
            float rx = fminf(ax2[g], v.z), ry = fminf(ay2[g], v.w);
            float w = fmaxf(rx - lx, 0.0f), h = fmaxf(ry - ly, 0.0f);
            float inter = w * h;
            float iou = inter * fast_rcp(aar[g] + sa - inter);
            if (iou > best[g]) { best[g] = iou; bi[g] = n; }   // row: first box
            if (iou > cbest) { cbest = iou; ca = (unsigned)(abase + g * BLOCK + tid); }
        }
        unsigned long long pk = ((unsigned long long)__float_as_uint(cbest) << 32)
                              | (unsigned long long)(0xFFFFFFFFu - ca);
        unsigned long long cur = sbest[n];                 // broadcast read
        if (pk > cur) atomicMax(&sbest[n], pk);            // rare, monotone
    }
    __syncthreads();

    // column partials: one per (block, box), plain coalesced store
    if (tid < NN)
        packed_part[(size_t)slab * BN + (size_t)b * NN + tid] = sbest[tid];

    // row outputs: sole writer
    #pragma unroll
    for (int g = 0; g < GA; ++g) {
        const size_t idx = (size_t)b * A + abase + g * BLOCK + tid;
        max_iou_anchor[idx] = best[g];
        box_indice[idx] = bi[g];
    }
}

// ---------------------------------------------------------------------------
// Combine: reduce NSLAB partials -> packed; fused override scatter into
// box_indice via atomicMax(n | FLAG). Flagged values (>= FLAG) always beat
// pass-A values (< N); max over flagged n == segment_max semantics.
// ---------------------------------------------------------------------------
__global__ void __launch_bounds__(BLOCK) bbp_combine(
    const unsigned long long* __restrict__ packed_part,  // [NSLAB][BN]
    unsigned long long* __restrict__ packed,             // [BN]
    int* __restrict__ box_indice,                        // [B,A]
    int A, int BN) {
    int i = blockIdx.x * BLOCK + threadIdx.x;
    if (i >= BN) return;
    unsigned long long m = 0ull;
    #pragma unroll 8
    for (int p = 0; p < NSLAB; ++p) {
        unsigned long long o = packed_part[(size_t)p * BN + i];
        if (o > m) m = o;
    }
    packed[i] = m;
    int b = i / NN;
    int n = i - b * NN;
    unsigned an = 0xFFFFFFFFu - (unsigned)(m & 0xFFFFFFFFull);
    atomicMax(&box_indice[(size_t)b * A + an], n | FLAG);
}

// ---------------------------------------------------------------------------
// Finalize: decode override flag, score, one-hot conf, delta encoding.
// ---------------------------------------------------------------------------
__global__ void __launch_bounds__(BLOCK) bbp_finalize(
    const float* __restrict__ anchors, const float* __restrict__ bboxes,
    const int* __restrict__ labels, const float* __restrict__ mean4,
    const float* __restrict__ std4, const float* __restrict__ thr_p,
    const float* __restrict__ max_iou_anchor, const int* __restrict__ box_indice,
    const unsigned long long* __restrict__ packed,
    float* __restrict__ out_conf, float* __restrict__ out_deltas,
    int A, int N, int C) {
    const int b = blockIdx.y;
    const int a = blockIdx.x * BLOCK + threadIdx.x;
    if (a >= A) return;
    const float thr = thr_p[0];
    const size_t idx = (size_t)b * A + a;

    int w = box_indice[idx];
    bool valid = (w >= FLAG);
    int bi = valid ? (w & (FLAG - 1)) : w;
    unsigned long long pk = packed[(size_t)b * N + bi];
    float mb = __uint_as_float((unsigned)(pk >> 32));   // max_iou_of_bbox[bi]
    float miou = valid ? mb : max_iou_anchor[idx];
    float denom = fmaxf(mb, thr);
    if (miou < thr * 0.5f) miou = 0.0f;
    float score = miou * fast_rcp(denom);
    int lab = labels[(size_t)b * N + bi];
    if (lab <= 0) { score = 0.0f; lab = 0; }

    for (int c = 0; c < C; ++c)
        out_conf[idx * C + c] = (lab == c + 1) ? score : 0.0f;

    float4 bb = *(const float4*)(bboxes + ((size_t)b * N + bi) * 4);
    float4 ac = *(const float4*)(anchors + (size_t)a * 4);
    float cx = (bb.x + bb.z) * 0.5f;
    float cy = (bb.y + bb.w) * 0.5f;
    float bw = bb.z - bb.x;
    float bh = bb.w - bb.y;
    const float rz = fast_rcp(ac.z), rw = fast_rcp(ac.w);
    float4 d;
    d.x = ((cx - ac.x) * rz - mean4[0]) * fast_rcp(std4[0]);
    d.y = ((cy - ac.y) * rw - mean4[1]) * fast_rcp(std4[1]);
    d.z = (__logf(bw * rz) - mean4[2]) * fast_rcp(std4[2]);
    d.w = (__logf(bh * rw) - mean4[3]) * fast_rcp(std4[3]);
    *(float4*)(out_deltas + idx * 4) = d;
}

// ---------------------------------------------------------------------------
extern "C" void kernel_launch(void* const* d_in, const int* in_sizes, int n_in,
                              void* d_out, int out_size, void* d_ws, size_t ws_size,
                              hipStream_t stream) {
    const float* anchors = (const float*)d_in[0];
    const int* labels = (const int*)d_in[1];
    const float* bboxes = (const float*)d_in[2];
    const float* mean4 = (const float*)d_in[3];
    const float* std4 = (const float*)d_in[4];
    const float* thr_p = (const float*)d_in[5];

    const int A = in_sizes[0] / 4;        // 65536
    const int BN = in_sizes[1];           // 800
    const int N = NN;                     // 100
    const int B = BN / N;                 // 8
    const int C = out_size / (B * A) - 4; // 1

    char* ws = (char*)d_ws;
    unsigned long long* packed_part = (unsigned long long*)ws;  // [NSLAB*BN] = 819 KB
    size_t off = ((size_t)NSLAB * BN * sizeof(unsigned long long) + 255) & ~(size_t)255;
    unsigned long long* packed = (unsigned long long*)(ws + off);
    off += ((size_t)BN * sizeof(unsigned long long) + 255) & ~(size_t)255;
    float* max_iou_anchor = (float*)(ws + off); off += (size_t)B * A * sizeof(float);
    off = (off + 255) & ~(size_t)255;
    int* box_indice = (int*)(ws + off);

    float* out_conf = (float*)d_out;
    float* out_deltas = out_conf + (size_t)B * A * C;

    bbp_match<<<dim3(B * NSLAB), dim3(BLOCK), 0, stream>>>(
        anchors, bboxes, max_iou_anchor, box_indice, packed_part, A, BN);

    bbp_combine<<<dim3((BN + BLOCK - 1) / BLOCK), dim3(BLOCK), 0, stream>>>(
        packed_part, packed, box_indice, A, BN);

    dim3 grid(A / BLOCK, B);
    bbp_finalize<<<grid, dim3(BLOCK), 0, stream>>>(anchors, bboxes, labels, mean4, std4,
                                                   thr_p, max_iou_anchor, box_indice,
                                                   packed, out_conf, out_deltas,
                                                   A, N, C);
}

// Round 11
// 124.706 us; speedup vs baseline: 4.6034x; 4.6034x over previous
//
#include <hip/hip_runtime.h>
#include <math.h>

#define BLOCK 256
#define NN 100
#define GB 4             // boxes per pass-B block
#define NGRP (NN / GB)   // 25 box-groups per image
#define SPLIT 16         // anchor-dimension splits for pass B
#define FLAG 0x40000000  // "override winner" marker in box_indice

__device__ __forceinline__ float fast_rcp(float x) { return __builtin_amdgcn_rcpf(x); }

// ---------------------------------------------------------------------------
// Fused match kernel (R8 structure + 128-VGPR budget + deferred rcp).
//  blocks [0, NAB)          : pass A — per-anchor row max over 100 boxes.
//  blocks [NAB, NAB + NBB)  : pass B — per-box partial column max over a
//                             4096-anchor slab, plain store (sole writer).
// Best tracked as (inter, union); comparisons via cross-multiply (exact
// first-occurrence argmax under strict >); single rcp at the end.
// ---------------------------------------------------------------------------
__global__ void __launch_bounds__(BLOCK, 4) bbp_fused(
    const float* __restrict__ anchors,            // [A,4] cbox (cx,cy,w,h)
    const float* __restrict__ bboxes,             // [B,N,4] bbox
    float* __restrict__ max_iou_anchor,           // [B,A]
    int* __restrict__ box_indice,                 // [B,A]
    unsigned long long* __restrict__ packed_part, // [B,N,SPLIT]
    int A, int NA, int NAB) {
    const int bid = blockIdx.x;
    const int tid = threadIdx.x;

    if (bid < NAB) {
        // ========== pass A: per-anchor max/argmax over boxes ================
        const int b = bid / NA;
        const int a = (bid - b * NA) * BLOCK + tid;

        __shared__ float sarea[NN];
        if (tid < NN) {
            float4 v = *(const float4*)(bboxes + ((size_t)b * NN + tid) * 4);
            sarea[tid] = (v.z - v.x) * (v.w - v.y);
        }
        __syncthreads();

        const float4 ac = *(const float4*)(anchors + (size_t)a * 4);
        const float ax1 = fmaf(ac.z, -0.5f, ac.x);
        const float ay1 = fmaf(ac.w, -0.5f, ac.y);
        const float ax2 = fmaf(ac.z, 0.5f, ac.x);
        const float ay2 = fmaf(ac.w, 0.5f, ac.y);
        const float area_a = ac.z * ac.w;

        const float* bbase = bboxes + (size_t)b * NN * 4;   // wave-uniform

        float bin = -1.0f, bun = 1.0f;   // best (inter, union)
        int bi = 0;
        #pragma unroll 10
        for (int n = 0; n < NN; ++n) {
            const float4 v = *(const float4*)(bbase + 4 * n);  // uniform -> s_load
            const float sa = sarea[n];                         // LDS broadcast
            float lx = fmaxf(ax1, v.x), ly = fmaxf(ay1, v.y);
            float rx = fminf(ax2, v.z), ry = fminf(ay2, v.w);
            float w = fmaxf(rx - lx, 0.0f), h = fmaxf(ry - ly, 0.0f);
            float inter = w * h;
            float uni = area_a + sa - inter;
            // inter/uni > bin/bun  <=>  inter*bun > bin*uni  (both uni,bun > 0
            // after first iter; init (-1,1) makes n=0 always win)
            if (inter * bun > bin * uni) { bin = inter; bun = uni; bi = n; }
        }
        const size_t idx = (size_t)b * A + a;
        max_iou_anchor[idx] = bin * fast_rcp(bun);
        box_indice[idx] = bi;
    } else {
        // ========== pass B: per-box partial max over one anchor slab ========
        const int pb = bid - NAB;
        const int b = pb / (NGRP * SPLIT);
        const int rem = pb - b * (NGRP * SPLIT);
        const int ng = rem / SPLIT;
        const int sp = rem - ng * SPLIT;
        const int n0 = ng * GB;
        const int SA = A / SPLIT;                 // 4096 anchors per slab
        const int abase = sp * SA;
        const float* bb = bboxes + ((size_t)b * NN + n0) * 4;

        float bx1[GB], by1[GB], bx2[GB], by2[GB], sa[GB];
        #pragma unroll
        for (int g = 0; g < GB; ++g) {
            float4 v = *(const float4*)(bb + 4 * g);     // uniform -> s_load
            bx1[g] = v.x; by1[g] = v.y; bx2[g] = v.z; by2[g] = v.w;
            sa[g] = (v.z - v.x) * (v.w - v.y);
        }
        float cin[GB], cun[GB];
        int cai[GB];
        #pragma unroll
        for (int g = 0; g < GB; ++g) { cin[g] = -1.0f; cun[g] = 1.0f; cai[g] = abase + tid; }

        const int iters = SA >> 8;                       // 16
        #pragma unroll 4
        for (int j = 0; j < iters; ++j) {
            const int a = abase + j * BLOCK + tid;
            const float4 ac = *(const float4*)(anchors + (size_t)a * 4); // coalesced
            const float ax1 = fmaf(ac.z, -0.5f, ac.x);
            const float ay1 = fmaf(ac.w, -0.5f, ac.y);
            const float ax2 = fmaf(ac.z, 0.5f, ac.x);
            const float ay2 = fmaf(ac.w, 0.5f, ac.y);
            const float area_a = ac.z * ac.w;
            #pragma unroll
            for (int g = 0; g < GB; ++g) {
                float lx = fmaxf(ax1, bx1[g]), ly = fmaxf(ay1, by1[g]);
                float rx = fminf(ax2, bx2[g]), ry = fminf(ay2, by2[g]);
                float w = fmaxf(rx - lx, 0.0f), h = fmaxf(ry - ly, 0.0f);
                float inter = w * h;
                float uni = area_a + sa[g] - inter;
                if (inter * cun[g] > cin[g] * uni) {      // strict >: smallest a
                    cin[g] = inter; cun[g] = uni; cai[g] = a;
                }
            }
        }

        // once-per-block combine: shfl-u64 wave reduce -> LDS -> plain store
        __shared__ unsigned long long sred[GB][BLOCK / 64];
        #pragma unroll
        for (int g = 0; g < GB; ++g) {
            float iou = cin[g] * fast_rcp(cun[g]);        // single rcp per (thread,box)
            iou = fmaxf(iou, 0.0f);
            unsigned long long pk =
                ((unsigned long long)__float_as_uint(iou) << 32)
                | (unsigned long long)(0xFFFFFFFFu - (unsigned)cai[g]);
            #pragma unroll
            for (int off = 32; off > 0; off >>= 1) {
                unsigned long long o = __shfl_down(pk, off, 64);
                if (o > pk) pk = o;
            }
            if ((tid & 63) == 0) sred[g][tid >> 6] = pk;
        }
        __syncthreads();
        if (tid < GB) {
            unsigned long long m = sred[tid][0];
            #pragma unroll
            for (int j = 1; j < BLOCK / 64; ++j) {
                unsigned long long o = sred[tid][j];
                if (o > m) m = o;
            }
            packed_part[(((size_t)b * NN + n0 + tid) * SPLIT) + sp] = m;
        }
    }
}

// ---------------------------------------------------------------------------
// Combine: reduce SPLIT partials -> packed; fused override scatter into
// box_indice via atomicMax(n | FLAG). Flagged values (>= FLAG) always beat
// pass-A values (< N); max over flagged n == segment_max semantics.
// ---------------------------------------------------------------------------
__global__ void __launch_bounds__(BLOCK) bbp_combine(
    const unsigned long long* __restrict__ packed_part,  // [B,N,SPLIT]
    unsigned long long* __restrict__ packed,             // [BN]
    int* __restrict__ box_indice,                        // [B,A]
    int A, int total) {
    int i = blockIdx.x * BLOCK + threadIdx.x;
    if (i >= total) return;
    unsigned long long m = packed_part[(size_t)i * SPLIT];
    #pragma unroll
    for (int j = 1; j < SPLIT; ++j) {
        unsigned long long o = packed_part[(size_t)i * SPLIT + j];
        if (o > m) m = o;
    }
    packed[i] = m;
    int b = i / NN;
    int n = i - b * NN;
    unsigned an = 0xFFFFFFFFu - (unsigned)(m & 0xFFFFFFFFull);
    atomicMax(&box_indice[(size_t)b * A + an], n | FLAG);
}

// ---------------------------------------------------------------------------
// Finalize: decode override flag, score, one-hot conf, delta encoding.
// ---------------------------------------------------------------------------
__global__ void __launch_bounds__(BLOCK) bbp_finalize(
    const float* __restrict__ anchors, const float* __restrict__ bboxes,
    const int* __restrict__ labels, const float* __restrict__ mean4,
    const float* __restrict__ std4, const float* __restrict__ thr_p,
    const float* __restrict__ max_iou_anchor, const int* __restrict__ box_indice,
    const unsigned long long* __restrict__ packed,
    float* __restrict__ out_conf, float* __restrict__ out_deltas,
    int A, int N, int C) {
    const int b = blockIdx.y;
    const int a = blockIdx.x * BLOCK + threadIdx.x;
    if (a >= A) return;
    const float thr = thr_p[0];
    const size_t idx = (size_t)b * A + a;

    int w = box_indice[idx];
    bool valid = (w >= FLAG);
    int bi = valid ? (w & (FLAG - 1)) : w;
    unsigned long long pk = packed[(size_t)b * N + bi];
    float mb = __uint_as_float((unsigned)(pk >> 32));   // max_iou_of_bbox[bi]
    float miou = valid ? mb : max_iou_anchor[idx];
    float denom = fmaxf(mb, thr);
    if (miou < thr * 0.5f) miou = 0.0f;
    float score = miou * fast_rcp(denom);
    int lab = labels[(size_t)b * N + bi];
    if (lab <= 0) { score = 0.0f; lab = 0; }

    for (int c = 0; c < C; ++c)
        out_conf[idx * C + c] = (lab == c + 1) ? score : 0.0f;

    float4 bb = *(const float4*)(bboxes + ((size_t)b * N + bi) * 4);
    float4 ac = *(const float4*)(anchors + (size_t)a * 4);
    float cx = (bb.x + bb.z) * 0.5f;
    float cy = (bb.y + bb.w) * 0.5f;
    float bw = bb.z - bb.x;
    float bh = bb.w - bb.y;
    const float rz = fast_rcp(ac.z), rw = fast_rcp(ac.w);
    float4 d;
    d.x = ((cx - ac.x) * rz - mean4[0]) * fast_rcp(std4[0]);
    d.y = ((cy - ac.y) * rw - mean4[1]) * fast_rcp(std4[1]);
    d.z = (__logf(bw * rz) - mean4[2]) * fast_rcp(std4[2]);
    d.w = (__logf(bh * rw) - mean4[3]) * fast_rcp(std4[3]);
    *(float4*)(out_deltas + idx * 4) = d;
}

// ---------------------------------------------------------------------------
extern "C" void kernel_launch(void* const* d_in, const int* in_sizes, int n_in,
                              void* d_out, int out_size, void* d_ws, size_t ws_size,
                              hipStream_t stream) {
    const float* anchors = (const float*)d_in[0];
    const int* labels = (const int*)d_in[1];
    const float* bboxes = (const float*)d_in[2];
    const float* mean4 = (const float*)d_in[3];
    const float* std4 = (const float*)d_in[4];
    const float* thr_p = (const float*)d_in[5];

    const int A = in_sizes[0] / 4;        // 65536
    const int BN = in_sizes[1];           // 800
    const int N = NN;                     // 100
    const int B = BN / N;                 // 8
    const int C = out_size / (B * A) - 4; // 1
    const int NA = A / BLOCK;             // 256 pass-A block-groups per image
    const int NAB = B * NA;               // 2048 pass-A blocks
    const int NBB = B * NGRP * SPLIT;     // 3200 pass-B blocks

    char* ws = (char*)d_ws;
    unsigned long long* packed_part = (unsigned long long*)ws;                 // [B*N*SPLIT]
    size_t off = ((size_t)B * N * SPLIT * sizeof(unsigned long long) + 255) & ~(size_t)255;
    unsigned long long* packed = (unsigned long long*)(ws + off);
    off += ((size_t)B * N * sizeof(unsigned long long) + 255) & ~(size_t)255;
    float* max_iou_anchor = (float*)(ws + off); off += (size_t)B * A * sizeof(float);
    off = (off + 255) & ~(size_t)255;
    int* box_indice = (int*)(ws + off);

    float* out_conf = (float*)d_out;
    float* out_deltas = out_conf + (size_t)B * A * C;

    bbp_fused<<<dim3(NAB + NBB), dim3(BLOCK), 0, stream>>>(
        anchors, bboxes, max_iou_anchor, box_indice, packed_part, A, NA, NAB);

    bbp_combine<<<dim3((B * N + BLOCK - 1) / BLOCK), dim3(BLOCK), 0, stream>>>(
        packed_part, packed, box_indice, A, B * N);

    dim3 grid(A / BLOCK, B);
    bbp_finalize<<<grid, dim3(BLOCK), 0, stream>>>(anchors, bboxes, labels, mean4, std4,
                                                   thr_p, max_iou_anchor, box_indice,
                                                   packed, out_conf, out_deltas,
                                                   A, N, C);
}